// Round 1
// baseline (2133.916 us; speedup 1.0000x reference)
//
#include <hip/hip_runtime.h>

#define SEQ 2048
#define BATCH 512
#define HDIM 128

__device__ __forceinline__ float fast_tanh(float x) {
    // tanh(x) = 1 - 2/(exp(2x)+1); exact limits at +/-inf via v_exp/v_rcp.
    float e = __expf(2.0f * x);
    return fmaf(-2.0f, __builtin_amdgcn_rcpf(e + 1.0f), 1.0f);
}

__global__ __launch_bounds__(256, 2)
void odenet_scan_kernel(const float* __restrict__ x,
                        const float* __restrict__ W1,
                        const float* __restrict__ b1,
                        const float* __restrict__ W2,
                        const float* __restrict__ b2,
                        const float* __restrict__ W3,
                        const float* __restrict__ b3,
                        float* __restrict__ out)
{
    const int t = threadIdx.x;
    const int b = blockIdx.x;          // one chain (batch element) per block
    const int q = t >> 7;              // K-half: 0 or 1
    const int c = t & 127;             // output column

    __shared__ float h1s[HDIM];
    __shared__ float pbuf[256];
    __shared__ float ybuf[2];

    // Pin this thread's half-column of W2 in VGPRs (loaded once, reused 2048x).
    float w2r[64];
    #pragma unroll
    for (int i = 0; i < 64; ++i)
        w2r[i] = W2[(q * 64 + i) * HDIM + c];

    // Layer-1 / layer-3 per-column weights (used by t<128 path only).
    const float w1x = W1[c];           // W1[0][c]
    const float w1s = W1[HDIM + c];    // W1[1][c]
    const float b1v = b1[c];
    const float b2v = b2[c];
    const float w3v = W3[2 * c + 1];   // W3[c][1] — only column 1 survives
    const float b31 = b3[1];

    float s = 0.0f;
    float xn = x[b];                   // x[0][b][0], layout (S,B,1)

    for (int n = 0; n < SEQ; ++n) {
        // Prefetch next step's input early (uniform per block).
        float xnext = 0.0f;
        if (t < 128 && n + 1 < SEQ) xnext = x[(n + 1) * BATCH + b];

        if (t < 128) {
            float pre = fmaf(w1x, xn, fmaf(w1s, s, b1v));
            h1s[t] = fast_tanh(pre);
        }
        __syncthreads();

        // 128x128 matvec, split-K by 2: 64 FMAs vs broadcast float4 LDS reads.
        float p = 0.0f;
        const float4* h4 = (const float4*)(&h1s[q * 64]);
        #pragma unroll
        for (int k = 0; k < 16; ++k) {
            float4 hv = h4[k];
            p = fmaf(w2r[4 * k + 0], hv.x, p);
            p = fmaf(w2r[4 * k + 1], hv.y, p);
            p = fmaf(w2r[4 * k + 2], hv.z, p);
            p = fmaf(w2r[4 * k + 3], hv.w, p);
        }
        pbuf[t] = p;
        __syncthreads();

        if (t < 128) {
            float h2 = fast_tanh(pbuf[t] + pbuf[t + 128] + b2v);
            float z = h2 * w3v;
            // 64-lane butterfly reduce
            #pragma unroll
            for (int off = 32; off > 0; off >>= 1)
                z += __shfl_xor(z, off, 64);
            if ((t & 63) == 0) ybuf[t >> 6] = z;
        }
        __syncthreads();

        if (t < 128) {
            s = s + ybuf[0] + ybuf[1] + b31;
            if (t == 0) out[n * BATCH + b] = s;
            xn = xnext;
        }
    }
}

extern "C" void kernel_launch(void* const* d_in, const int* in_sizes, int n_in,
                              void* d_out, int out_size, void* d_ws, size_t ws_size,
                              hipStream_t stream) {
    const float* x  = (const float*)d_in[0];
    const float* W1 = (const float*)d_in[1];
    const float* b1 = (const float*)d_in[2];
    const float* W2 = (const float*)d_in[3];
    const float* b2 = (const float*)d_in[4];
    const float* W3 = (const float*)d_in[5];
    const float* b3 = (const float*)d_in[6];
    float* out = (float*)d_out;

    dim3 grid(BATCH);
    dim3 block(256);
    odenet_scan_kernel<<<grid, block, 0, stream>>>(x, W1, b1, W2, b2, W3, b3, out);
}

// Round 2
// 1580.846 us; speedup vs baseline: 1.3499x; 1.3499x over previous
//
#include <hip/hip_runtime.h>

#define SEQ 2048
#define BATCH 512
#define HDIM 128

__device__ __forceinline__ float fast_tanh(float x) {
    // tanh(x) = 1 - 2/(exp(2x)+1); exact saturation at +/-inf.
    float e = __expf(2.0f * x);
    return fmaf(-2.0f, __builtin_amdgcn_rcpf(e + 1.0f), 1.0f);
}

// DPP move with compile-time control; old=0 so invalid/unselected lanes add 0.
template<int CTRL>
__device__ __forceinline__ float dpp_mov(float x) {
    return __int_as_float(__builtin_amdgcn_update_dpp(
        0, __float_as_int(x), CTRL, 0xf, 0xf, false));
}

__global__ __launch_bounds__(128, 1)
void odenet_scan_kernel(const float* __restrict__ x,
                        const float* __restrict__ W1,
                        const float* __restrict__ b1,
                        const float* __restrict__ W2,
                        const float* __restrict__ b2,
                        const float* __restrict__ W3,
                        const float* __restrict__ b3,
                        float* __restrict__ out)
{
    const int t = threadIdx.x;      // 0..127
    const int b = blockIdx.x;       // one chain per block
    const int q = t >> 6;           // wave index = K-half
    const int l = t & 63;           // lane

    __shared__ float h1s[HDIM];           // wave-private halves, no cross-wave access
    __shared__ float pbuf[2][2][HDIM];    // [parity][wave][col] split-K partials

    // Pin this wave's K-half of W2 in VGPRs: rows 64q..64q+63, cols l and l+64.
    float w2a[64], w2b[64];
    #pragma unroll
    for (int i = 0; i < 64; ++i) {
        w2a[i] = W2[(q * 64 + i) * HDIM + l];
        w2b[i] = W2[(q * 64 + i) * HDIM + l + 64];
    }

    const int ch = q * 64 + l;            // h1 column this lane computes
    const float w1x = W1[ch];             // W1[0][ch]
    const float w1s = W1[HDIM + ch];      // W1[1][ch]
    const float b1v = b1[ch];

    const float b2_0 = b2[l];
    const float b2_1 = b2[l + 64];
    const float w3_0 = W3[2 * l + 1];         // only column 1 of W3 survives
    const float w3_1 = W3[2 * (l + 64) + 1];
    const float b31  = b3[1];

    float s = 0.0f;
    float xn = x[b];                      // x[0][b][0], layout (S,B,1)

    for (int n = 0; n < SEQ; ++n) {
        const int par = n & 1;

        // ---- layer 1: each lane computes one h column of its wave's half.
        float pre = fmaf(w1x, xn, fmaf(w1s, s, b1v));
        h1s[ch] = fast_tanh(pre);

        // prefetch next step's x (wave-uniform address -> scalar load path)
        float xnext = (n + 1 < SEQ) ? x[(n + 1) * BATCH + b] : 0.0f;

        // ---- layer 2 matvec: this wave's K-half, all 128 cols (2 per lane).
        // Reads only the h-half this wave just wrote: no barrier, lgkmcnt only.
        float pa = 0.0f, pb = 0.0f;
        const float4* h4 = (const float4*)(&h1s[q * 64]);
        #pragma unroll
        for (int k = 0; k < 16; ++k) {
            float4 hv = h4[k];
            pa = fmaf(w2a[4 * k + 0], hv.x, pa);
            pb = fmaf(w2b[4 * k + 0], hv.x, pb);
            pa = fmaf(w2a[4 * k + 1], hv.y, pa);
            pb = fmaf(w2b[4 * k + 1], hv.y, pb);
            pa = fmaf(w2a[4 * k + 2], hv.z, pa);
            pb = fmaf(w2b[4 * k + 2], hv.z, pb);
            pa = fmaf(w2a[4 * k + 3], hv.w, pa);
            pb = fmaf(w2b[4 * k + 3], hv.w, pb);
        }
        pbuf[par][q][l]      = pa;
        pbuf[par][q][l + 64] = pb;
        __syncthreads();   // the ONLY barrier per step (parity dbuf => race-free)

        // ---- combine split-K + tanh + W3 column-1 dot: both waves redundantly.
        float h2_0 = fast_tanh(pbuf[par][0][l]      + pbuf[par][1][l]      + b2_0);
        float h2_1 = fast_tanh(pbuf[par][0][l + 64] + pbuf[par][1][l + 64] + b2_1);
        float z = fmaf(h2_0, w3_0, h2_1 * w3_1);

        // wave64 sum via DPP: row_shr 1,2,4,8 then row_bcast15, row_bcast31.
        z += dpp_mov<0x111>(z);
        z += dpp_mov<0x112>(z);
        z += dpp_mov<0x114>(z);
        z += dpp_mov<0x118>(z);
        z += dpp_mov<0x142>(z);
        z += dpp_mov<0x143>(z);
        float y = __int_as_float(__builtin_amdgcn_readlane(__float_as_int(z), 63));

        s = s + y + b31;
        if (t == 0) out[n * BATCH + b] = s;
        xn = xnext;
    }
}

extern "C" void kernel_launch(void* const* d_in, const int* in_sizes, int n_in,
                              void* d_out, int out_size, void* d_ws, size_t ws_size,
                              hipStream_t stream) {
    const float* x  = (const float*)d_in[0];
    const float* W1 = (const float*)d_in[1];
    const float* b1 = (const float*)d_in[2];
    const float* W2 = (const float*)d_in[3];
    const float* b2 = (const float*)d_in[4];
    const float* W3 = (const float*)d_in[5];
    const float* b3 = (const float*)d_in[6];
    float* out = (float*)d_out;

    dim3 grid(BATCH);
    dim3 block(128);
    odenet_scan_kernel<<<grid, block, 0, stream>>>(x, W1, b1, W2, b2, W3, b3, out);
}